// Round 6
// baseline (479.251 us; speedup 1.0000x reference)
//
#include <hip/hip_runtime.h>
#include <hip/hip_bf16.h>

#define N_NODES 50000
#define E_EDGES 800000
#define ET (E_EDGES + N_NODES)   /* 850000 edges incl self loops */
#define IN_DIM 128
#define HID 96
#define HEADS 2
#define CPH 48
#define NEG_SLOPE 0.2f
#define LN_EPS 1e-5f
#define CHUNK 24                 /* edges per softmax/agg chunk */
#define LROW 50                  /* LDS dwords per staged edge row (48 payload + 2 pad) */
#define PBASE (CHUNK * LROW)     /* start of p area, dwords */
#define WTILE (PBASE + 2 * CHUNK)/* per-wave LDS dwords: 1248 -> 4992 B */

typedef __hip_bfloat16 bf16;
typedef short bf16x8 __attribute__((ext_vector_type(8)));
typedef float f32x4 __attribute__((ext_vector_type(4)));
typedef _Float16 h16;
typedef h16 h16x2 __attribute__((ext_vector_type(2)));
typedef h16 h16x8 __attribute__((ext_vector_type(8)));

#if __has_builtin(__builtin_amdgcn_fdot2)
#define HAS_FDOT2 1
#else
#define HAS_FDOT2 0
#endif

__device__ __forceinline__ unsigned short f2bf(float f) {
    union { float f; unsigned int i; } u; u.f = f;
    unsigned int r = u.i + 0x7FFFu + ((u.i >> 16) & 1u);
    return (unsigned short)(r >> 16);
}

// ---------------- CSR build ----------------
__global__ void k_hist(const int* __restrict__ ei, int* __restrict__ deg) {
    int e = blockIdx.x * blockDim.x + threadIdx.x;
    if (e >= ET) return;
    int dst = (e < E_EDGES) ? ei[E_EDGES + e] : (e - E_EDGES);
    atomicAdd(&deg[dst], 1);
}

__global__ __launch_bounds__(1024) void k_scan(const int* __restrict__ deg,
                                               int* __restrict__ rowstart,
                                               int* __restrict__ cursor) {
    __shared__ int wsum[16];
    __shared__ int s_carry;
    int t = threadIdx.x, lane = t & 63, w = t >> 6;
    if (t == 0) s_carry = 0;
    __syncthreads();
    for (int base = 0; base < N_NODES; base += 1024) {
        int i = base + t;
        int v = (i < N_NODES) ? deg[i] : 0;
        int sv = v;
        for (int o = 1; o < 64; o <<= 1) { int u = __shfl_up(sv, o, 64); if (lane >= o) sv += u; }
        if (lane == 63) wsum[w] = sv;
        __syncthreads();
        if (w == 0) {
            int val = (lane < 16) ? wsum[lane] : 0;
            int s2 = val;
            for (int o = 1; o < 64; o <<= 1) { int u = __shfl_up(s2, o, 64); if (lane >= o) s2 += u; }
            if (lane < 16) wsum[lane] = s2 - val;            // exclusive wave prefix
        }
        __syncthreads();
        int excl = s_carry + wsum[w] + (sv - v);
        if (i < N_NODES) { rowstart[i] = excl; cursor[i] = excl; }
        __syncthreads();
        if (t == 1023) s_carry += wsum[15] + sv;
        __syncthreads();
    }
    if (t == 0) rowstart[N_NODES] = ET;
}

__global__ void k_scatter(const int* __restrict__ ei, int* __restrict__ cursor,
                          int* __restrict__ csr_src) {
    int e = blockIdx.x * blockDim.x + threadIdx.x;
    if (e >= ET) return;
    int src, dst;
    if (e < E_EDGES) { src = ei[e]; dst = ei[E_EDGES + e]; }
    else             { src = dst = e - E_EDGES; }
    int pos = atomicAdd(&cursor[dst], 1);
    csr_src[pos] = src;
}

// ---------------- weight prep: pack into 16x16x32 B-fragment order, bf16 ----------------
__global__ void k_wprep(const float* __restrict__ W0, const float* __restrict__ W1,
                        unsigned short* __restrict__ out, int NT, int total) {
    int idx = blockIdx.x * blockDim.x + threadIdx.x;
    if (idx >= total) return;
    int j = idx & 7, lane = (idx >> 3) & 63;
    int nt = (idx >> 9) % NT, ks = (idx >> 9) / NT;
    int k = ks * 32 + ((lane >> 4) << 3) + j;
    int col = nt * 16 + (lane & 15);
    float v = (col < HID) ? W0[k * HID + col] : W1[k * HID + col - HID];
    out[idx] = f2bf(v);
}

// ---------------- MFMA GEMM: A[f32, MxK] @ Bfrag -> proj(LN+ReLU->h) or xfm(->xl,xr fp16) ----------------
template<int K, int NT, bool PROJ>
__global__ __launch_bounds__(256) void k_gemm(const float* __restrict__ A,
                                              const unsigned short* __restrict__ Bfrag,
                                              const float* __restrict__ bp,
                                              const float* __restrict__ g0,
                                              const float* __restrict__ b0,
                                              float* __restrict__ hout,
                                              h16* __restrict__ xl,
                                              h16* __restrict__ xr) {
    constexpr int KS = K / 32;
    int t = threadIdx.x, l = t & 63, w = t >> 6;
    int row0 = blockIdx.x * 64 + w * 16;
    int arow = row0 + (l & 15);
    if (arow > N_NODES - 1) arow = N_NODES - 1;
    int kb = (l >> 4) * 8;
    const float* ap = A + (long)arow * K + kb;
    bf16x8 a[KS];
    #pragma unroll
    for (int ks = 0; ks < KS; ks++) {
        float4 f0 = *(const float4*)(ap + ks * 32);
        float4 f1 = *(const float4*)(ap + ks * 32 + 4);
        bf16x8 av;
        av[0] = (short)f2bf(f0.x); av[1] = (short)f2bf(f0.y);
        av[2] = (short)f2bf(f0.z); av[3] = (short)f2bf(f0.w);
        av[4] = (short)f2bf(f1.x); av[5] = (short)f2bf(f1.y);
        av[6] = (short)f2bf(f1.z); av[7] = (short)f2bf(f1.w);
        a[ks] = av;
    }
    f32x4 acc[NT];
    #pragma unroll
    for (int nt = 0; nt < NT; nt++) acc[nt] = (f32x4){0.f, 0.f, 0.f, 0.f};
    #pragma unroll
    for (int nt = 0; nt < NT; nt++) {
        #pragma unroll
        for (int ks = 0; ks < KS; ks++) {
            bf16x8 b = *(const bf16x8*)(Bfrag + (((long)(ks * NT + nt) * 64 + l) << 3));
            acc[nt] = __builtin_amdgcn_mfma_f32_16x16x32_bf16(a[ks], b, acc[nt], 0, 0, 0);
        }
    }
    int rg = l >> 4, cl = l & 15;
    if constexpr (PROJ) {
        float bpv[NT], g0v[NT], b0v[NT];
        #pragma unroll
        for (int nt = 0; nt < NT; nt++) {
            int col = nt * 16 + cl;
            bpv[nt] = bp[col]; g0v[nt] = g0[col]; b0v[nt] = b0[col];
        }
        #pragma unroll
        for (int r = 0; r < 4; r++) {
            float s = 0.f, sq = 0.f;
            #pragma unroll
            for (int nt = 0; nt < NT; nt++) {
                float v = acc[nt][r] + bpv[nt];
                acc[nt][r] = v; s += v; sq += v * v;
            }
            #pragma unroll
            for (int o = 1; o <= 8; o <<= 1) { s += __shfl_xor(s, o, 64); sq += __shfl_xor(sq, o, 64); }
            float mu = s / (float)HID;
            float var = sq / (float)HID - mu * mu;
            float rstd = rsqrtf(var + LN_EPS);
            int row = row0 + rg * 4 + r;
            if (row < N_NODES) {
                #pragma unroll
                for (int nt = 0; nt < NT; nt++) {
                    float y = (acc[nt][r] - mu) * rstd * g0v[nt] + b0v[nt];
                    hout[(long)row * HID + nt * 16 + cl] = fmaxf(y, 0.f);
                }
            }
        }
    } else {
        #pragma unroll
        for (int r = 0; r < 4; r++) {
            int row = row0 + rg * 4 + r;
            if (row < N_NODES) {
                #pragma unroll
                for (int nt = 0; nt < NT; nt++) {
                    int col = nt * 16 + cl;
                    h16 v = (h16)acc[nt][r];
                    if (col < HID) xl[(long)row * HID + col] = v;
                    else           xr[(long)row * HID + col - HID] = v;
                }
            }
        }
    }
}

// ---------------- fused: edge scores + online softmax + aggregate + LN + ELU + residual ----------------
// One wave per node; 4 waves/block, private LDS tiles; no __syncthreads.
// Score: lane = hh*32+j (j<CHUNK) scores edge (base+j) for head hh, stages xl row slice to LDS.
// p staged to LDS; agg: lane l<48 owns channel pair {2l,2l+1}; p read as broadcast float4,
// x read via offset-immediate ds_read_b32. No per-edge shuffles.
__global__ __launch_bounds__(256, 8) void k_node_fused(const int* __restrict__ rowstart,
                                                       const int* __restrict__ csr_src,
                                                       const h16* __restrict__ xl,
                                                       const h16* __restrict__ xr,
                                                       const float* __restrict__ att,
                                                       const float* __restrict__ gs,
                                                       const float* __restrict__ bs,
                                                       float* __restrict__ h,
                                                       float* __restrict__ out,
                                                       int write_out) {
    __shared__ float lds[4 * WTILE];
    int t = threadIdx.x, lane = t & 63, w = t >> 6;
    float* slds = lds + w * WTILE;                 // x-stage: edge i at dwords [i*LROW .. +47]
    float* pbuf = slds + PBASE;                    // p: head hh at [hh*CHUNK + j]
    int n = blockIdx.x * 4 + w;                    // grid = N/4 exact
    int j = lane & 31, hh = lane >> 5;
    bool jok = (j < CHUNK);
    int rs = rowstart[n], re = rowstart[n + 1];

    // target row (this node) + attention vector for this lane's head, in regs
    const h16x8* xrr = (const h16x8*)(xr + (long)n * HID + hh * CPH);
    h16x8 xrv[6];
    #pragma unroll
    for (int v = 0; v < 6; v++) xrv[v] = xrr[v];
    const float* ar = att + hh * CPH;
    h16x8 attv[6];
    #pragma unroll
    for (int v = 0; v < 6; v++) {
        float4 t0 = *(const float4*)(ar + v * 8);
        float4 t1 = *(const float4*)(ar + v * 8 + 4);
        attv[v] = (h16x8){(h16)t0.x, (h16)t0.y, (h16)t0.z, (h16)t0.w,
                          (h16)t1.x, (h16)t1.y, (h16)t1.z, (h16)t1.w};
    }

    float M = -INFINITY, D = 0.f;                  // per 32-lane half = per head
    int l = lane;
    int lc = (l < 48) ? l : 47;                    // channel pair owned (lanes>=48 shadow 47)
    bool hi = (lc >= 24);                          // which head's p/D this lane consumes
    float2 acc = {0.f, 0.f};

    for (int base = rs; base < re; base += CHUNK) {
        int L = min(CHUNK, re - base);
        float s = -INFINITY;
        if (jok) {
            int srcj = csr_src[base + min(j, L - 1)];
            const h16x8* xlr = (const h16x8*)(xl + (long)srcj * HID + hh * CPH);
            float s0 = 0.f, s1 = 0.f;
#if !HAS_FDOT2
            h16x8 sacc = (h16x8)(h16)0.f;
#endif
            #pragma unroll
            for (int v = 0; v < 6; v++) {
                h16x8 xa = xlr[v];
                *(h16x8*)(slds + j * LROW + hh * 24 + v * 4) = xa;   // stage (offset-imm)
                h16x8 sum = xa + xrv[v];
                h16x8 lk = __builtin_elementwise_max(sum, sum * (h16)NEG_SLOPE);
#if HAS_FDOT2
                s0 = __builtin_amdgcn_fdot2(__builtin_shufflevector(lk, lk, 0, 1),
                                            __builtin_shufflevector(attv[v], attv[v], 0, 1), s0, false);
                s1 = __builtin_amdgcn_fdot2(__builtin_shufflevector(lk, lk, 2, 3),
                                            __builtin_shufflevector(attv[v], attv[v], 2, 3), s1, false);
                s0 = __builtin_amdgcn_fdot2(__builtin_shufflevector(lk, lk, 4, 5),
                                            __builtin_shufflevector(attv[v], attv[v], 4, 5), s0, false);
                s1 = __builtin_amdgcn_fdot2(__builtin_shufflevector(lk, lk, 6, 7),
                                            __builtin_shufflevector(attv[v], attv[v], 6, 7), s1, false);
#else
                sacc += lk * attv[v];
#endif
            }
#if !HAS_FDOT2
            {
                h16x2 p0 = __builtin_shufflevector(sacc, sacc, 0, 1);
                h16x2 p1 = __builtin_shufflevector(sacc, sacc, 2, 3);
                h16x2 p2 = __builtin_shufflevector(sacc, sacc, 4, 5);
                h16x2 p3 = __builtin_shufflevector(sacc, sacc, 6, 7);
                h16x2 q = (p0 + p1) + (p2 + p3);
                s0 = (float)q.x + (float)q.y; s1 = 0.f;
            }
#endif
            if (j < L) s = s0 + s1;
        }
        // online softmax update within each 32-lane half
        float m = s;
        #pragma unroll
        for (int o = 1; o <= 16; o <<= 1) m = fmaxf(m, __shfl_xor(m, o, 64));
        float newM = fmaxf(M, m);
        float scale = __expf(M - newM);             // exp(-inf)=0 on first chunk
        float p = (jok && j < L) ? __expf(s - newM) : 0.f;
        float sum = p;
        #pragma unroll
        for (int o = 1; o <= 16; o <<= 1) sum += __shfl_xor(sum, o, 64);
        D = D * scale + sum;
        M = newM;
        if (jok) pbuf[hh * CHUNK + j] = p;          // padding slots get p=0

        float sc0 = __shfl(scale, 0, 64), sc1 = __shfl(scale, 32, 64);
        float mysc = hi ? sc1 : sc0;
        acc.x *= mysc; acc.y *= mysc;

        const float* prow = pbuf + (hi ? CHUNK : 0);
        #pragma unroll
        for (int i4 = 0; i4 < CHUNK / 4; i4++) {
            if (i4 * 4 >= L) break;
            float4 pv = *(const float4*)(prow + i4 * 4);
            #pragma unroll
            for (int k = 0; k < 4; k++) {
                h16x2 hv = ((const h16x2*)(slds + (i4 * 4 + k) * LROW))[lc];
                float pk = ((const float*)&pv)[k];
                acc.x += pk * (float)hv.x;
                acc.y += pk * (float)hv.y;
            }
        }
    }
    float D0 = __shfl(D, 0, 64), D1 = __shfl(D, 32, 64);
    float myD = hi ? D1 : D0;
    float oa = acc.x / myD, ob = acc.y / myD;
    bool act = (l < 48);
    if (!act) { oa = 0.f; ob = 0.f; }
    // LayerNorm over 96 channels via full-wave reduce
    float s1r = oa + ob, s2r = oa * oa + ob * ob;
    #pragma unroll
    for (int o = 1; o <= 32; o <<= 1) { s1r += __shfl_xor(s1r, o, 64); s2r += __shfl_xor(s2r, o, 64); }
    float mu = s1r / (float)HID;
    float var = s2r / (float)HID - mu * mu;
    float rstd = rsqrtf(var + LN_EPS);
    if (act) {
        long baseo = (long)n * HID + 2 * l;
        float2 g = *(const float2*)(gs + 2 * l);
        float2 b = *(const float2*)(bs + 2 * l);
        float y0 = (oa - mu) * rstd * g.x + b.x;
        float y1 = (ob - mu) * rstd * g.y + b.y;
        float hn0 = (y0 > 0.f) ? y0 : expm1f(y0);
        float hn1 = (y1 > 0.f) ? y1 : expm1f(y1);
        float2 hold = *(float2*)(h + baseo);
        float2 hv = {hold.x + hn0, hold.y + hn1};
        *(float2*)(h + baseo) = hv;
        if (write_out) *(float2*)(out + baseo) = hv;
    }
}

extern "C" void kernel_launch(void* const* d_in, const int* in_sizes, int n_in,
                              void* d_out, int out_size, void* d_ws, size_t ws_size,
                              hipStream_t stream) {
    const float* x   = (const float*)d_in[0];
    const int*   ei  = (const int*)d_in[1];
    const float* Wp  = (const float*)d_in[2];
    const float* bp  = (const float*)d_in[3];
    const float* g0  = (const float*)d_in[4];
    const float* b0  = (const float*)d_in[5];
    const float* Wl  = (const float*)d_in[6];
    const float* Wr  = (const float*)d_in[7];
    const float* att = (const float*)d_in[8];
    const float* gs  = (const float*)d_in[9];
    const float* bs  = (const float*)d_in[10];
    float* out = (float*)d_out;

    char* wsp = (char*)d_ws;
    size_t off = 0;
    auto alloc = [&](size_t bytes) { void* p = wsp + off; off += (bytes + 255) / 256 * 256; return p; };
    float* h        = (float*)alloc((size_t)N_NODES * HID * 4);
    h16*   xl       = (h16*)  alloc((size_t)N_NODES * HID * 2);
    h16*   xr       = (h16*)  alloc((size_t)N_NODES * HID * 2);
    int*   deg      = (int*)  alloc((size_t)N_NODES * 4);
    int*   rowst    = (int*)  alloc((size_t)(N_NODES + 1) * 4);
    int*   cursor   = (int*)  alloc((size_t)N_NODES * 4);
    int*   csr_src  = (int*)  alloc((size_t)ET * 4);
    unsigned short* wp_frag = (unsigned short*)alloc((size_t)IN_DIM * HID * 2);
    unsigned short* wc_frag = (unsigned short*)alloc((size_t)2 * HID * 2 * HID * 2);

    hipMemsetAsync(deg, 0, (size_t)N_NODES * 4, stream);
    k_hist<<<(ET + 255) / 256, 256, 0, stream>>>(ei, deg);
    k_scan<<<1, 1024, 0, stream>>>(deg, rowst, cursor);
    k_scatter<<<(ET + 255) / 256, 256, 0, stream>>>(ei, cursor, csr_src);

    const int WPTOT = IN_DIM * HID;            // KS=4, NT=6
    const int WCTOT = HID * 2 * HID;           // per layer: KS=3, NT=12
    k_wprep<<<(WPTOT + 255) / 256, 256, 0, stream>>>(Wp, Wp, wp_frag, 6, WPTOT);
    for (int L = 0; L < 2; L++)
        k_wprep<<<(WCTOT + 255) / 256, 256, 0, stream>>>(Wl + (size_t)L * HID * HID,
                                                         Wr + (size_t)L * HID * HID,
                                                         wc_frag + (size_t)L * WCTOT, 12, WCTOT);

    const int GBLK = (N_NODES + 63) / 64;
    k_gemm<IN_DIM, 6, true><<<GBLK, 256, 0, stream>>>(x, wp_frag, bp, g0, b0, h, nullptr, nullptr);
    for (int L = 0; L < 2; L++) {
        k_gemm<HID, 12, false><<<GBLK, 256, 0, stream>>>(h, wc_frag + (size_t)L * WCTOT,
                                                         nullptr, nullptr, nullptr, nullptr, xl, xr);
        k_node_fused<<<N_NODES / 4, 256, 0, stream>>>(rowst, csr_src, xl, xr,
                                                      att + (size_t)L * HEADS * CPH,
                                                      gs + (size_t)L * HID, bs + (size_t)L * HID,
                                                      h, out, (L == 1) ? 1 : 0);
    }
}

// Round 7
// 342.568 us; speedup vs baseline: 1.3990x; 1.3990x over previous
//
#include <hip/hip_runtime.h>
#include <hip/hip_bf16.h>

#define N_NODES 50000
#define E_EDGES 800000
#define ET (E_EDGES + N_NODES)   /* 850000 edges incl self loops */
#define IN_DIM 128
#define HID 96
#define HEADS 2
#define CPH 48
#define NEG_SLOPE 0.2f
#define LN_EPS 1e-5f
#define CHUNK 24                 /* edges per softmax/agg chunk */
#define LROW 50                  /* LDS dwords per staged edge row (48 payload + 2 pad) */
#define PBASE (CHUNK * LROW)     /* start of p area, dwords */
#define WTILE (PBASE + 2 * CHUNK)/* per-wave LDS dwords: 1248 -> 4992 B */

typedef __hip_bfloat16 bf16;
typedef short bf16x8 __attribute__((ext_vector_type(8)));
typedef float f32x4 __attribute__((ext_vector_type(4)));
typedef _Float16 h16;
typedef h16 h16x2 __attribute__((ext_vector_type(2)));
typedef h16 h16x8 __attribute__((ext_vector_type(8)));

#if __has_builtin(__builtin_amdgcn_fdot2)
#define HAS_FDOT2 1
#else
#define HAS_FDOT2 0
#endif

__device__ __forceinline__ unsigned short f2bf(float f) {
    union { float f; unsigned int i; } u; u.f = f;
    unsigned int r = u.i + 0x7FFFu + ((u.i >> 16) & 1u);
    return (unsigned short)(r >> 16);
}

// ---------------- CSR build ----------------
__global__ void k_hist(const int* __restrict__ ei, int* __restrict__ deg) {
    int e = blockIdx.x * blockDim.x + threadIdx.x;
    if (e >= ET) return;
    int dst = (e < E_EDGES) ? ei[E_EDGES + e] : (e - E_EDGES);
    atomicAdd(&deg[dst], 1);
}

__global__ __launch_bounds__(1024) void k_scan(const int* __restrict__ deg,
                                               int* __restrict__ rowstart,
                                               int* __restrict__ cursor) {
    __shared__ int wsum[16];
    __shared__ int s_carry;
    int t = threadIdx.x, lane = t & 63, w = t >> 6;
    if (t == 0) s_carry = 0;
    __syncthreads();
    for (int base = 0; base < N_NODES; base += 1024) {
        int i = base + t;
        int v = (i < N_NODES) ? deg[i] : 0;
        int sv = v;
        for (int o = 1; o < 64; o <<= 1) { int u = __shfl_up(sv, o, 64); if (lane >= o) sv += u; }
        if (lane == 63) wsum[w] = sv;
        __syncthreads();
        if (w == 0) {
            int val = (lane < 16) ? wsum[lane] : 0;
            int s2 = val;
            for (int o = 1; o < 64; o <<= 1) { int u = __shfl_up(s2, o, 64); if (lane >= o) s2 += u; }
            if (lane < 16) wsum[lane] = s2 - val;            // exclusive wave prefix
        }
        __syncthreads();
        int excl = s_carry + wsum[w] + (sv - v);
        if (i < N_NODES) { rowstart[i] = excl; cursor[i] = excl; }
        __syncthreads();
        if (t == 1023) s_carry += wsum[15] + sv;
        __syncthreads();
    }
    if (t == 0) rowstart[N_NODES] = ET;
}

__global__ void k_scatter(const int* __restrict__ ei, int* __restrict__ cursor,
                          int* __restrict__ csr_src) {
    int e = blockIdx.x * blockDim.x + threadIdx.x;
    if (e >= ET) return;
    int src, dst;
    if (e < E_EDGES) { src = ei[e]; dst = ei[E_EDGES + e]; }
    else             { src = dst = e - E_EDGES; }
    int pos = atomicAdd(&cursor[dst], 1);
    csr_src[pos] = src;
}

// ---------------- weight prep: pack into 16x16x32 B-fragment order, bf16 ----------------
__global__ void k_wprep(const float* __restrict__ W0, const float* __restrict__ W1,
                        unsigned short* __restrict__ out, int NT, int total) {
    int idx = blockIdx.x * blockDim.x + threadIdx.x;
    if (idx >= total) return;
    int j = idx & 7, lane = (idx >> 3) & 63;
    int nt = (idx >> 9) % NT, ks = (idx >> 9) / NT;
    int k = ks * 32 + ((lane >> 4) << 3) + j;
    int col = nt * 16 + (lane & 15);
    float v = (col < HID) ? W0[k * HID + col] : W1[k * HID + col - HID];
    out[idx] = f2bf(v);
}

// ---------------- MFMA GEMM: A[f32, MxK] @ Bfrag -> proj(LN+ReLU->h) or xfm(->xl,xr fp16) ----------------
template<int K, int NT, bool PROJ>
__global__ __launch_bounds__(256) void k_gemm(const float* __restrict__ A,
                                              const unsigned short* __restrict__ Bfrag,
                                              const float* __restrict__ bp,
                                              const float* __restrict__ g0,
                                              const float* __restrict__ b0,
                                              float* __restrict__ hout,
                                              h16* __restrict__ xl,
                                              h16* __restrict__ xr) {
    constexpr int KS = K / 32;
    int t = threadIdx.x, l = t & 63, w = t >> 6;
    int row0 = blockIdx.x * 64 + w * 16;
    int arow = row0 + (l & 15);
    if (arow > N_NODES - 1) arow = N_NODES - 1;
    int kb = (l >> 4) * 8;
    const float* ap = A + (long)arow * K + kb;
    bf16x8 a[KS];
    #pragma unroll
    for (int ks = 0; ks < KS; ks++) {
        float4 f0 = *(const float4*)(ap + ks * 32);
        float4 f1 = *(const float4*)(ap + ks * 32 + 4);
        bf16x8 av;
        av[0] = (short)f2bf(f0.x); av[1] = (short)f2bf(f0.y);
        av[2] = (short)f2bf(f0.z); av[3] = (short)f2bf(f0.w);
        av[4] = (short)f2bf(f1.x); av[5] = (short)f2bf(f1.y);
        av[6] = (short)f2bf(f1.z); av[7] = (short)f2bf(f1.w);
        a[ks] = av;
    }
    f32x4 acc[NT];
    #pragma unroll
    for (int nt = 0; nt < NT; nt++) acc[nt] = (f32x4){0.f, 0.f, 0.f, 0.f};
    #pragma unroll
    for (int nt = 0; nt < NT; nt++) {
        #pragma unroll
        for (int ks = 0; ks < KS; ks++) {
            bf16x8 b = *(const bf16x8*)(Bfrag + (((long)(ks * NT + nt) * 64 + l) << 3));
            acc[nt] = __builtin_amdgcn_mfma_f32_16x16x32_bf16(a[ks], b, acc[nt], 0, 0, 0);
        }
    }
    int rg = l >> 4, cl = l & 15;
    if constexpr (PROJ) {
        float bpv[NT], g0v[NT], b0v[NT];
        #pragma unroll
        for (int nt = 0; nt < NT; nt++) {
            int col = nt * 16 + cl;
            bpv[nt] = bp[col]; g0v[nt] = g0[col]; b0v[nt] = b0[col];
        }
        #pragma unroll
        for (int r = 0; r < 4; r++) {
            float s = 0.f, sq = 0.f;
            #pragma unroll
            for (int nt = 0; nt < NT; nt++) {
                float v = acc[nt][r] + bpv[nt];
                acc[nt][r] = v; s += v; sq += v * v;
            }
            #pragma unroll
            for (int o = 1; o <= 8; o <<= 1) { s += __shfl_xor(s, o, 64); sq += __shfl_xor(sq, o, 64); }
            float mu = s / (float)HID;
            float var = sq / (float)HID - mu * mu;
            float rstd = rsqrtf(var + LN_EPS);
            int row = row0 + rg * 4 + r;
            if (row < N_NODES) {
                #pragma unroll
                for (int nt = 0; nt < NT; nt++) {
                    float y = (acc[nt][r] - mu) * rstd * g0v[nt] + b0v[nt];
                    hout[(long)row * HID + nt * 16 + cl] = fmaxf(y, 0.f);
                }
            }
        }
    } else {
        #pragma unroll
        for (int r = 0; r < 4; r++) {
            int row = row0 + rg * 4 + r;
            if (row < N_NODES) {
                #pragma unroll
                for (int nt = 0; nt < NT; nt++) {
                    int col = nt * 16 + cl;
                    h16 v = (h16)acc[nt][r];
                    if (col < HID) xl[(long)row * HID + col] = v;
                    else           xr[(long)row * HID + col - HID] = v;
                }
            }
        }
    }
}

// ---------------- fused: edge scores + online softmax + aggregate + LN + ELU + residual ----------------
// One wave per node; 4 waves/block, private LDS tiles; no __syncthreads.
// NOTE: plain __launch_bounds__(256) — round 6's (256,8) forced VGPR 64->32 and spilled
// ~660 MB of scratch traffic per dispatch (WRITE_SIZE 37.5->375 MB). Keep VGPR=64, no spill;
// occupancy comes from the LDS shrink (19968 B/block -> 8 blocks/CU).
__global__ __launch_bounds__(256) void k_node_fused(const int* __restrict__ rowstart,
                                                    const int* __restrict__ csr_src,
                                                    const h16* __restrict__ xl,
                                                    const h16* __restrict__ xr,
                                                    const float* __restrict__ att,
                                                    const float* __restrict__ gs,
                                                    const float* __restrict__ bs,
                                                    float* __restrict__ h,
                                                    float* __restrict__ out,
                                                    int write_out) {
    __shared__ float lds[4 * WTILE];
    int t = threadIdx.x, lane = t & 63, w = t >> 6;
    float* slds = lds + w * WTILE;                 // x-stage: edge i at dwords [i*LROW .. +47]
    float* pbuf = slds + PBASE;                    // p: head hh at [hh*CHUNK + j]
    int n = blockIdx.x * 4 + w;                    // grid = N/4 exact
    int j = lane & 31, hh = lane >> 5;
    bool jok = (j < CHUNK);
    int rs = rowstart[n], re = rowstart[n + 1];

    // target row (this node) + attention vector for this lane's head, in regs
    const h16x8* xrr = (const h16x8*)(xr + (long)n * HID + hh * CPH);
    h16x8 xrv[6];
    #pragma unroll
    for (int v = 0; v < 6; v++) xrv[v] = xrr[v];
    const float* ar = att + hh * CPH;
    h16x8 attv[6];
    #pragma unroll
    for (int v = 0; v < 6; v++) {
        float4 t0 = *(const float4*)(ar + v * 8);
        float4 t1 = *(const float4*)(ar + v * 8 + 4);
        attv[v] = (h16x8){(h16)t0.x, (h16)t0.y, (h16)t0.z, (h16)t0.w,
                          (h16)t1.x, (h16)t1.y, (h16)t1.z, (h16)t1.w};
    }

    float M = -INFINITY, D = 0.f;                  // per 32-lane half = per head
    int l = lane;
    int lc = (l < 48) ? l : 47;                    // channel pair owned (lanes>=48 shadow 47)
    bool hi = (lc >= 24);                          // which head's p/D this lane consumes
    float2 acc = {0.f, 0.f};

    for (int base = rs; base < re; base += CHUNK) {
        int L = min(CHUNK, re - base);
        float s = -INFINITY;
        if (jok) {
            int srcj = csr_src[base + min(j, L - 1)];
            const h16x8* xlr = (const h16x8*)(xl + (long)srcj * HID + hh * CPH);
            float s0 = 0.f, s1 = 0.f;
#if !HAS_FDOT2
            h16x8 sacc = (h16x8)(h16)0.f;
#endif
            #pragma unroll
            for (int v = 0; v < 6; v++) {
                h16x8 xa = xlr[v];
                *(h16x8*)(slds + j * LROW + hh * 24 + v * 4) = xa;   // stage (offset-imm)
                h16x8 sum = xa + xrv[v];
                h16x8 lk = __builtin_elementwise_max(sum, sum * (h16)NEG_SLOPE);
#if HAS_FDOT2
                s0 = __builtin_amdgcn_fdot2(__builtin_shufflevector(lk, lk, 0, 1),
                                            __builtin_shufflevector(attv[v], attv[v], 0, 1), s0, false);
                s1 = __builtin_amdgcn_fdot2(__builtin_shufflevector(lk, lk, 2, 3),
                                            __builtin_shufflevector(attv[v], attv[v], 2, 3), s1, false);
                s0 = __builtin_amdgcn_fdot2(__builtin_shufflevector(lk, lk, 4, 5),
                                            __builtin_shufflevector(attv[v], attv[v], 4, 5), s0, false);
                s1 = __builtin_amdgcn_fdot2(__builtin_shufflevector(lk, lk, 6, 7),
                                            __builtin_shufflevector(attv[v], attv[v], 6, 7), s1, false);
#else
                sacc += lk * attv[v];
#endif
            }
#if !HAS_FDOT2
            {
                h16x2 p0 = __builtin_shufflevector(sacc, sacc, 0, 1);
                h16x2 p1 = __builtin_shufflevector(sacc, sacc, 2, 3);
                h16x2 p2 = __builtin_shufflevector(sacc, sacc, 4, 5);
                h16x2 p3 = __builtin_shufflevector(sacc, sacc, 6, 7);
                h16x2 q = (p0 + p1) + (p2 + p3);
                s0 = (float)q.x + (float)q.y; s1 = 0.f;
            }
#endif
            if (j < L) s = s0 + s1;
        }
        // online softmax update within each 32-lane half
        float m = s;
        #pragma unroll
        for (int o = 1; o <= 16; o <<= 1) m = fmaxf(m, __shfl_xor(m, o, 64));
        float newM = fmaxf(M, m);
        float scale = __expf(M - newM);             // exp(-inf)=0 on first chunk
        float p = (jok && j < L) ? __expf(s - newM) : 0.f;
        float sum = p;
        #pragma unroll
        for (int o = 1; o <= 16; o <<= 1) sum += __shfl_xor(sum, o, 64);
        D = D * scale + sum;
        M = newM;
        if (jok) pbuf[hh * CHUNK + j] = p;          // padding slots get p=0

        float sc0 = __shfl(scale, 0, 64), sc1 = __shfl(scale, 32, 64);
        float mysc = hi ? sc1 : sc0;
        acc.x *= mysc; acc.y *= mysc;

        const float* prow = pbuf + (hi ? CHUNK : 0);
        #pragma unroll
        for (int i4 = 0; i4 < CHUNK / 4; i4++) {
            if (i4 * 4 >= L) break;
            float4 pv = *(const float4*)(prow + i4 * 4);
            #pragma unroll
            for (int k = 0; k < 4; k++) {
                h16x2 hv = ((const h16x2*)(slds + (i4 * 4 + k) * LROW))[lc];
                float pk = ((const float*)&pv)[k];
                acc.x += pk * (float)hv.x;
                acc.y += pk * (float)hv.y;
            }
        }
    }
    float D0 = __shfl(D, 0, 64), D1 = __shfl(D, 32, 64);
    float myD = hi ? D1 : D0;
    float oa = acc.x / myD, ob = acc.y / myD;
    bool act = (l < 48);
    if (!act) { oa = 0.f; ob = 0.f; }
    // LayerNorm over 96 channels via full-wave reduce
    float s1r = oa + ob, s2r = oa * oa + ob * ob;
    #pragma unroll
    for (int o = 1; o <= 32; o <<= 1) { s1r += __shfl_xor(s1r, o, 64); s2r += __shfl_xor(s2r, o, 64); }
    float mu = s1r / (float)HID;
    float var = s2r / (float)HID - mu * mu;
    float rstd = rsqrtf(var + LN_EPS);
    if (act) {
        long baseo = (long)n * HID + 2 * l;
        float2 g = *(const float2*)(gs + 2 * l);
        float2 b = *(const float2*)(bs + 2 * l);
        float y0 = (oa - mu) * rstd * g.x + b.x;
        float y1 = (ob - mu) * rstd * g.y + b.y;
        float hn0 = (y0 > 0.f) ? y0 : expm1f(y0);
        float hn1 = (y1 > 0.f) ? y1 : expm1f(y1);
        float2 hold = *(float2*)(h + baseo);
        float2 hv = {hold.x + hn0, hold.y + hn1};
        *(float2*)(h + baseo) = hv;
        if (write_out) *(float2*)(out + baseo) = hv;
    }
}

extern "C" void kernel_launch(void* const* d_in, const int* in_sizes, int n_in,
                              void* d_out, int out_size, void* d_ws, size_t ws_size,
                              hipStream_t stream) {
    const float* x   = (const float*)d_in[0];
    const int*   ei  = (const int*)d_in[1];
    const float* Wp  = (const float*)d_in[2];
    const float* bp  = (const float*)d_in[3];
    const float* g0  = (const float*)d_in[4];
    const float* b0  = (const float*)d_in[5];
    const float* Wl  = (const float*)d_in[6];
    const float* Wr  = (const float*)d_in[7];
    const float* att = (const float*)d_in[8];
    const float* gs  = (const float*)d_in[9];
    const float* bs  = (const float*)d_in[10];
    float* out = (float*)d_out;

    char* wsp = (char*)d_ws;
    size_t off = 0;
    auto alloc = [&](size_t bytes) { void* p = wsp + off; off += (bytes + 255) / 256 * 256; return p; };
    float* h        = (float*)alloc((size_t)N_NODES * HID * 4);
    h16*   xl       = (h16*)  alloc((size_t)N_NODES * HID * 2);
    h16*   xr       = (h16*)  alloc((size_t)N_NODES * HID * 2);
    int*   deg      = (int*)  alloc((size_t)N_NODES * 4);
    int*   rowst    = (int*)  alloc((size_t)(N_NODES + 1) * 4);
    int*   cursor   = (int*)  alloc((size_t)N_NODES * 4);
    int*   csr_src  = (int*)  alloc((size_t)ET * 4);
    unsigned short* wp_frag = (unsigned short*)alloc((size_t)IN_DIM * HID * 2);
    unsigned short* wc_frag = (unsigned short*)alloc((size_t)2 * HID * 2 * HID * 2);

    hipMemsetAsync(deg, 0, (size_t)N_NODES * 4, stream);
    k_hist<<<(ET + 255) / 256, 256, 0, stream>>>(ei, deg);
    k_scan<<<1, 1024, 0, stream>>>(deg, rowst, cursor);
    k_scatter<<<(ET + 255) / 256, 256, 0, stream>>>(ei, cursor, csr_src);

    const int WPTOT = IN_DIM * HID;            // KS=4, NT=6
    const int WCTOT = HID * 2 * HID;           // per layer: KS=3, NT=12
    k_wprep<<<(WPTOT + 255) / 256, 256, 0, stream>>>(Wp, Wp, wp_frag, 6, WPTOT);
    for (int L = 0; L < 2; L++)
        k_wprep<<<(WCTOT + 255) / 256, 256, 0, stream>>>(Wl + (size_t)L * HID * HID,
                                                         Wr + (size_t)L * HID * HID,
                                                         wc_frag + (size_t)L * WCTOT, 12, WCTOT);

    const int GBLK = (N_NODES + 63) / 64;
    k_gemm<IN_DIM, 6, true><<<GBLK, 256, 0, stream>>>(x, wp_frag, bp, g0, b0, h, nullptr, nullptr);
    for (int L = 0; L < 2; L++) {
        k_gemm<HID, 12, false><<<GBLK, 256, 0, stream>>>(h, wc_frag + (size_t)L * WCTOT,
                                                         nullptr, nullptr, nullptr, nullptr, xl, xr);
        k_node_fused<<<N_NODES / 4, 256, 0, stream>>>(rowst, csr_src, xl, xr,
                                                      att + (size_t)L * HEADS * CPH,
                                                      gs + (size_t)L * HID, bs + (size_t)L * HID,
                                                      h, out, (L == 1) ? 1 : 0);
    }
}

// Round 8
// 304.798 us; speedup vs baseline: 1.5724x; 1.1239x over previous
//
#include <hip/hip_runtime.h>
#include <hip/hip_bf16.h>

#define N_NODES 50000
#define E_EDGES 800000
#define ET (E_EDGES + N_NODES)   /* 850000 edges incl self loops */
#define IN_DIM 128
#define HID 96
#define HEADS 2
#define CPH 48
#define NEG_SLOPE 0.2f
#define LN_EPS 1e-5f
#define CHUNK 24                 /* edges per softmax/agg chunk */
#define LROW 50                  /* LDS dwords per staged edge row (48 payload + 2 pad) */
#define PBASE (CHUNK * LROW)     /* start of p area, dwords */
#define WTILE (PBASE + 2 * CHUNK)/* per-wave LDS dwords: 1248 -> 4992 B */
#define WPTOT (IN_DIM * HID)     /* 12288 = KS4 * NT6 * 512 */
#define WCTOT (HID * 2 * HID)    /* 18432 = KS3 * NT12 * 512, per layer */

typedef __hip_bfloat16 bf16;
typedef short bf16x8 __attribute__((ext_vector_type(8)));
typedef float f32x4 __attribute__((ext_vector_type(4)));
typedef _Float16 h16;
typedef h16 h16x2 __attribute__((ext_vector_type(2)));
typedef h16 h16x8 __attribute__((ext_vector_type(8)));

#if __has_builtin(__builtin_amdgcn_fdot2)
#define HAS_FDOT2 1
#else
#define HAS_FDOT2 0
#endif

__device__ __forceinline__ unsigned short f2bf(float f) {
    union { float f; unsigned int i; } u; u.f = f;
    unsigned int r = u.i + 0x7FFFu + ((u.i >> 16) & 1u);
    return (unsigned short)(r >> 16);
}

// ---------------- CSR build ----------------
__global__ void k_hist(const int* __restrict__ ei, int* __restrict__ deg) {
    int e = blockIdx.x * blockDim.x + threadIdx.x;
    if (e >= ET) return;
    int dst = (e < E_EDGES) ? ei[E_EDGES + e] : (e - E_EDGES);
    atomicAdd(&deg[dst], 1);
}

// single-block scan, 4 elements/thread (13 iterations over 50k)
__global__ __launch_bounds__(1024) void k_scan(const int* __restrict__ deg,
                                               int* __restrict__ rowstart,
                                               int* __restrict__ cursor) {
    __shared__ int wsum[16];
    __shared__ int s_carry;
    int t = threadIdx.x, lane = t & 63, w = t >> 6;
    if (t == 0) s_carry = 0;
    __syncthreads();
    for (int base = 0; base < N_NODES; base += 4096) {
        int i0 = base + t * 4;
        int4 d = {0, 0, 0, 0};
        if (i0 + 3 < N_NODES) d = *(const int4*)(deg + i0);
        else {
            if (i0 + 0 < N_NODES) d.x = deg[i0 + 0];
            if (i0 + 1 < N_NODES) d.y = deg[i0 + 1];
            if (i0 + 2 < N_NODES) d.z = deg[i0 + 2];
            if (i0 + 3 < N_NODES) d.w = deg[i0 + 3];
        }
        int e1 = d.x, e2 = d.x + d.y, e3 = d.x + d.y + d.z;
        int tot = e3 + d.w;
        int sv = tot;
        for (int o = 1; o < 64; o <<= 1) { int u = __shfl_up(sv, o, 64); if (lane >= o) sv += u; }
        if (lane == 63) wsum[w] = sv;
        __syncthreads();
        if (w == 0) {
            int val = (lane < 16) ? wsum[lane] : 0;
            int s2 = val;
            for (int o = 1; o < 64; o <<= 1) { int u = __shfl_up(s2, o, 64); if (lane >= o) s2 += u; }
            if (lane < 16) wsum[lane] = s2 - val;            // exclusive wave prefix
        }
        __syncthreads();
        int excl = s_carry + wsum[w] + (sv - tot);
        if (i0 + 3 < N_NODES) {
            int4 r = {excl, excl + e1, excl + e2, excl + e3};
            *(int4*)(rowstart + i0) = r;
            *(int4*)(cursor + i0) = r;
        } else {
            if (i0 + 0 < N_NODES) { rowstart[i0 + 0] = excl;      cursor[i0 + 0] = excl; }
            if (i0 + 1 < N_NODES) { rowstart[i0 + 1] = excl + e1; cursor[i0 + 1] = excl + e1; }
            if (i0 + 2 < N_NODES) { rowstart[i0 + 2] = excl + e2; cursor[i0 + 2] = excl + e2; }
            if (i0 + 3 < N_NODES) { rowstart[i0 + 3] = excl + e3; cursor[i0 + 3] = excl + e3; }
        }
        __syncthreads();
        if (t == 1023) s_carry += wsum[15] + sv;
        __syncthreads();
    }
    if (t == 0) rowstart[N_NODES] = ET;
}

__global__ void k_scatter(const int* __restrict__ ei, int* __restrict__ cursor,
                          int* __restrict__ csr_src) {
    int e = blockIdx.x * blockDim.x + threadIdx.x;
    if (e >= ET) return;
    int src, dst;
    if (e < E_EDGES) { src = ei[e]; dst = ei[E_EDGES + e]; }
    else             { src = dst = e - E_EDGES; }
    int pos = atomicAdd(&cursor[dst], 1);
    csr_src[pos] = src;
}

// ---------------- merged weight prep (all 3 GEMM weight sets) + deg zeroing ----------------
// frag layout per weight set: idx -> j=idx&7, lane=(idx>>3)&63, nt=(idx>>9)%NT, ks=(idx>>9)/NT
// source k = ks*32 + (lane>>4)*8 + j ; col = nt*16 + (lane&15)
__global__ void k_wprep_all(const float* __restrict__ Wp,
                            const float* __restrict__ Wl,
                            const float* __restrict__ Wr,
                            unsigned short* __restrict__ wp_frag,
                            unsigned short* __restrict__ wc_frag,
                            int* __restrict__ deg) {
    int idx = blockIdx.x * blockDim.x + threadIdx.x;
    if (idx < N_NODES) deg[idx] = 0;
    if (idx < WPTOT) {
        int j = idx & 7, lane = (idx >> 3) & 63;
        int nt = (idx >> 9) % 6, ks = (idx >> 9) / 6;
        int k = ks * 32 + ((lane >> 4) << 3) + j;
        int col = nt * 16 + (lane & 15);
        wp_frag[idx] = f2bf(Wp[k * HID + col]);           // col always < 96 (NT=6)
    } else if (idx < WPTOT + 2 * WCTOT) {
        int L = (idx - WPTOT) / WCTOT;
        int id = (idx - WPTOT) % WCTOT;
        int j = id & 7, lane = (id >> 3) & 63;
        int nt = (id >> 9) % 12, ks = (id >> 9) / 12;
        int k = ks * 32 + ((lane >> 4) << 3) + j;
        int col = nt * 16 + (lane & 15);
        const float* W0 = Wl + (size_t)L * HID * HID;
        const float* W1 = Wr + (size_t)L * HID * HID;
        float v = (col < HID) ? W0[k * HID + col] : W1[k * HID + col - HID];
        wc_frag[(size_t)L * WCTOT + id] = f2bf(v);
    }
}

// ---------------- MFMA GEMM: A[f32, MxK] @ Bfrag -> proj(LN+ReLU->h) or xfm(->xl,xr fp16) ----------------
template<int K, int NT, bool PROJ>
__global__ __launch_bounds__(256) void k_gemm(const float* __restrict__ A,
                                              const unsigned short* __restrict__ Bfrag,
                                              const float* __restrict__ bp,
                                              const float* __restrict__ g0,
                                              const float* __restrict__ b0,
                                              float* __restrict__ hout,
                                              h16* __restrict__ xl,
                                              h16* __restrict__ xr) {
    constexpr int KS = K / 32;
    int t = threadIdx.x, l = t & 63, w = t >> 6;
    int row0 = blockIdx.x * 64 + w * 16;
    int arow = row0 + (l & 15);
    if (arow > N_NODES - 1) arow = N_NODES - 1;
    int kb = (l >> 4) * 8;
    const float* ap = A + (long)arow * K + kb;
    bf16x8 a[KS];
    #pragma unroll
    for (int ks = 0; ks < KS; ks++) {
        float4 f0 = *(const float4*)(ap + ks * 32);
        float4 f1 = *(const float4*)(ap + ks * 32 + 4);
        bf16x8 av;
        av[0] = (short)f2bf(f0.x); av[1] = (short)f2bf(f0.y);
        av[2] = (short)f2bf(f0.z); av[3] = (short)f2bf(f0.w);
        av[4] = (short)f2bf(f1.x); av[5] = (short)f2bf(f1.y);
        av[6] = (short)f2bf(f1.z); av[7] = (short)f2bf(f1.w);
        a[ks] = av;
    }
    f32x4 acc[NT];
    #pragma unroll
    for (int nt = 0; nt < NT; nt++) acc[nt] = (f32x4){0.f, 0.f, 0.f, 0.f};
    #pragma unroll
    for (int nt = 0; nt < NT; nt++) {
        #pragma unroll
        for (int ks = 0; ks < KS; ks++) {
            bf16x8 b = *(const bf16x8*)(Bfrag + (((long)(ks * NT + nt) * 64 + l) << 3));
            acc[nt] = __builtin_amdgcn_mfma_f32_16x16x32_bf16(a[ks], b, acc[nt], 0, 0, 0);
        }
    }
    int rg = l >> 4, cl = l & 15;
    if constexpr (PROJ) {
        float bpv[NT], g0v[NT], b0v[NT];
        #pragma unroll
        for (int nt = 0; nt < NT; nt++) {
            int col = nt * 16 + cl;
            bpv[nt] = bp[col]; g0v[nt] = g0[col]; b0v[nt] = b0[col];
        }
        #pragma unroll
        for (int r = 0; r < 4; r++) {
            float s = 0.f, sq = 0.f;
            #pragma unroll
            for (int nt = 0; nt < NT; nt++) {
                float v = acc[nt][r] + bpv[nt];
                acc[nt][r] = v; s += v; sq += v * v;
            }
            #pragma unroll
            for (int o = 1; o <= 8; o <<= 1) { s += __shfl_xor(s, o, 64); sq += __shfl_xor(sq, o, 64); }
            float mu = s / (float)HID;
            float var = sq / (float)HID - mu * mu;
            float rstd = rsqrtf(var + LN_EPS);
            int row = row0 + rg * 4 + r;
            if (row < N_NODES) {
                #pragma unroll
                for (int nt = 0; nt < NT; nt++) {
                    float y = (acc[nt][r] - mu) * rstd * g0v[nt] + b0v[nt];
                    hout[(long)row * HID + nt * 16 + cl] = fmaxf(y, 0.f);
                }
            }
        }
    } else {
        #pragma unroll
        for (int r = 0; r < 4; r++) {
            int row = row0 + rg * 4 + r;
            if (row < N_NODES) {
                #pragma unroll
                for (int nt = 0; nt < NT; nt++) {
                    int col = nt * 16 + cl;
                    h16 v = (h16)acc[nt][r];
                    if (col < HID) xl[(long)row * HID + col] = v;
                    else           xr[(long)row * HID + col - HID] = v;
                }
            }
        }
    }
}

// ---------------- fused: edge scores + online softmax + aggregate + LN + ELU + residual ----------------
// UNCHANGED from round 7 (control). One wave per node; 4 waves/block; no __syncthreads.
// Plain __launch_bounds__(256): (256,8) forced VGPR 64->32 => 660 MB scratch spill (round 6).
__global__ __launch_bounds__(256) void k_node_fused(const int* __restrict__ rowstart,
                                                    const int* __restrict__ csr_src,
                                                    const h16* __restrict__ xl,
                                                    const h16* __restrict__ xr,
                                                    const float* __restrict__ att,
                                                    const float* __restrict__ gs,
                                                    const float* __restrict__ bs,
                                                    float* __restrict__ h,
                                                    float* __restrict__ out,
                                                    int write_out) {
    __shared__ float lds[4 * WTILE];
    int t = threadIdx.x, lane = t & 63, w = t >> 6;
    float* slds = lds + w * WTILE;                 // x-stage: edge i at dwords [i*LROW .. +47]
    float* pbuf = slds + PBASE;                    // p: head hh at [hh*CHUNK + j]
    int n = blockIdx.x * 4 + w;                    // grid = N/4 exact
    int j = lane & 31, hh = lane >> 5;
    bool jok = (j < CHUNK);
    int rs = rowstart[n], re = rowstart[n + 1];

    const h16x8* xrr = (const h16x8*)(xr + (long)n * HID + hh * CPH);
    h16x8 xrv[6];
    #pragma unroll
    for (int v = 0; v < 6; v++) xrv[v] = xrr[v];
    const float* ar = att + hh * CPH;
    h16x8 attv[6];
    #pragma unroll
    for (int v = 0; v < 6; v++) {
        float4 t0 = *(const float4*)(ar + v * 8);
        float4 t1 = *(const float4*)(ar + v * 8 + 4);
        attv[v] = (h16x8){(h16)t0.x, (h16)t0.y, (h16)t0.z, (h16)t0.w,
                          (h16)t1.x, (h16)t1.y, (h16)t1.z, (h16)t1.w};
    }

    float M = -INFINITY, D = 0.f;                  // per 32-lane half = per head
    int l = lane;
    int lc = (l < 48) ? l : 47;                    // channel pair owned (lanes>=48 shadow 47)
    bool hi = (lc >= 24);                          // which head's p/D this lane consumes
    float2 acc = {0.f, 0.f};

    for (int base = rs; base < re; base += CHUNK) {
        int L = min(CHUNK, re - base);
        float s = -INFINITY;
        if (jok) {
            int srcj = csr_src[base + min(j, L - 1)];
            const h16x8* xlr = (const h16x8*)(xl + (long)srcj * HID + hh * CPH);
            float s0 = 0.f, s1 = 0.f;
#if !HAS_FDOT2
            h16x8 sacc = (h16x8)(h16)0.f;
#endif
            #pragma unroll
            for (int v = 0; v < 6; v++) {
                h16x8 xa = xlr[v];
                *(h16x8*)(slds + j * LROW + hh * 24 + v * 4) = xa;   // stage (offset-imm)
                h16x8 sum = xa + xrv[v];
                h16x8 lk = __builtin_elementwise_max(sum, sum * (h16)NEG_SLOPE);
#if HAS_FDOT2
                s0 = __builtin_amdgcn_fdot2(__builtin_shufflevector(lk, lk, 0, 1),
                                            __builtin_shufflevector(attv[v], attv[v], 0, 1), s0, false);
                s1 = __builtin_amdgcn_fdot2(__builtin_shufflevector(lk, lk, 2, 3),
                                            __builtin_shufflevector(attv[v], attv[v], 2, 3), s1, false);
                s0 = __builtin_amdgcn_fdot2(__builtin_shufflevector(lk, lk, 4, 5),
                                            __builtin_shufflevector(attv[v], attv[v], 4, 5), s0, false);
                s1 = __builtin_amdgcn_fdot2(__builtin_shufflevector(lk, lk, 6, 7),
                                            __builtin_shufflevector(attv[v], attv[v], 6, 7), s1, false);
#else
                sacc += lk * attv[v];
#endif
            }
#if !HAS_FDOT2
            {
                h16x2 p0 = __builtin_shufflevector(sacc, sacc, 0, 1);
                h16x2 p1 = __builtin_shufflevector(sacc, sacc, 2, 3);
                h16x2 p2 = __builtin_shufflevector(sacc, sacc, 4, 5);
                h16x2 p3 = __builtin_shufflevector(sacc, sacc, 6, 7);
                h16x2 q = (p0 + p1) + (p2 + p3);
                s0 = (float)q.x + (float)q.y; s1 = 0.f;
            }
#endif
            if (j < L) s = s0 + s1;
        }
        float m = s;
        #pragma unroll
        for (int o = 1; o <= 16; o <<= 1) m = fmaxf(m, __shfl_xor(m, o, 64));
        float newM = fmaxf(M, m);
        float scale = __expf(M - newM);             // exp(-inf)=0 on first chunk
        float p = (jok && j < L) ? __expf(s - newM) : 0.f;
        float sum = p;
        #pragma unroll
        for (int o = 1; o <= 16; o <<= 1) sum += __shfl_xor(sum, o, 64);
        D = D * scale + sum;
        M = newM;
        if (jok) pbuf[hh * CHUNK + j] = p;          // padding slots get p=0

        float sc0 = __shfl(scale, 0, 64), sc1 = __shfl(scale, 32, 64);
        float mysc = hi ? sc1 : sc0;
        acc.x *= mysc; acc.y *= mysc;

        const float* prow = pbuf + (hi ? CHUNK : 0);
        #pragma unroll
        for (int i4 = 0; i4 < CHUNK / 4; i4++) {
            if (i4 * 4 >= L) break;
            float4 pv = *(const float4*)(prow + i4 * 4);
            #pragma unroll
            for (int k = 0; k < 4; k++) {
                h16x2 hv = ((const h16x2*)(slds + (i4 * 4 + k) * LROW))[lc];
                float pk = ((const float*)&pv)[k];
                acc.x += pk * (float)hv.x;
                acc.y += pk * (float)hv.y;
            }
        }
    }
    float D0 = __shfl(D, 0, 64), D1 = __shfl(D, 32, 64);
    float myD = hi ? D1 : D0;
    float oa = acc.x / myD, ob = acc.y / myD;
    bool act = (l < 48);
    if (!act) { oa = 0.f; ob = 0.f; }
    float s1r = oa + ob, s2r = oa * oa + ob * ob;
    #pragma unroll
    for (int o = 1; o <= 32; o <<= 1) { s1r += __shfl_xor(s1r, o, 64); s2r += __shfl_xor(s2r, o, 64); }
    float mu = s1r / (float)HID;
    float var = s2r / (float)HID - mu * mu;
    float rstd = rsqrtf(var + LN_EPS);
    if (act) {
        long baseo = (long)n * HID + 2 * l;
        float2 g = *(const float2*)(gs + 2 * l);
        float2 b = *(const float2*)(bs + 2 * l);
        float y0 = (oa - mu) * rstd * g.x + b.x;
        float y1 = (ob - mu) * rstd * g.y + b.y;
        float hn0 = (y0 > 0.f) ? y0 : expm1f(y0);
        float hn1 = (y1 > 0.f) ? y1 : expm1f(y1);
        float2 hold = *(float2*)(h + baseo);
        float2 hv = {hold.x + hn0, hold.y + hn1};
        *(float2*)(h + baseo) = hv;
        if (write_out) *(float2*)(out + baseo) = hv;
    }
}

extern "C" void kernel_launch(void* const* d_in, const int* in_sizes, int n_in,
                              void* d_out, int out_size, void* d_ws, size_t ws_size,
                              hipStream_t stream) {
    const float* x   = (const float*)d_in[0];
    const int*   ei  = (const int*)d_in[1];
    const float* Wp  = (const float*)d_in[2];
    const float* bp  = (const float*)d_in[3];
    const float* g0  = (const float*)d_in[4];
    const float* b0  = (const float*)d_in[5];
    const float* Wl  = (const float*)d_in[6];
    const float* Wr  = (const float*)d_in[7];
    const float* att = (const float*)d_in[8];
    const float* gs  = (const float*)d_in[9];
    const float* bs  = (const float*)d_in[10];
    float* out = (float*)d_out;

    char* wsp = (char*)d_ws;
    size_t off = 0;
    auto alloc = [&](size_t bytes) { void* p = wsp + off; off += (bytes + 255) / 256 * 256; return p; };
    float* h        = (float*)alloc((size_t)N_NODES * HID * 4);
    h16*   xl       = (h16*)  alloc((size_t)N_NODES * HID * 2);
    h16*   xr       = (h16*)  alloc((size_t)N_NODES * HID * 2);
    int*   deg      = (int*)  alloc((size_t)N_NODES * 4);
    int*   rowst    = (int*)  alloc((size_t)(N_NODES + 1) * 4);
    int*   cursor   = (int*)  alloc((size_t)N_NODES * 4);
    int*   csr_src  = (int*)  alloc((size_t)ET * 4);
    unsigned short* wp_frag = (unsigned short*)alloc((size_t)WPTOT * 2);
    unsigned short* wc_frag = (unsigned short*)alloc((size_t)2 * WCTOT * 2);

    // one merged prep kernel: zero deg + pack all 3 weight sets (saves memset + 2 launches)
    k_wprep_all<<<(N_NODES + 255) / 256, 256, 0, stream>>>(Wp, Wl, Wr, wp_frag, wc_frag, deg);
    k_hist<<<(ET + 255) / 256, 256, 0, stream>>>(ei, deg);
    k_scan<<<1, 1024, 0, stream>>>(deg, rowst, cursor);
    k_scatter<<<(ET + 255) / 256, 256, 0, stream>>>(ei, cursor, csr_src);

    const int GBLK = (N_NODES + 63) / 64;
    k_gemm<IN_DIM, 6, true><<<GBLK, 256, 0, stream>>>(x, wp_frag, bp, g0, b0, h, nullptr, nullptr);
    for (int L = 0; L < 2; L++) {
        k_gemm<HID, 12, false><<<GBLK, 256, 0, stream>>>(h, wc_frag + (size_t)L * WCTOT,
                                                         nullptr, nullptr, nullptr, nullptr, xl, xr);
        k_node_fused<<<N_NODES / 4, 256, 0, stream>>>(rowst, csr_src, xl, xr,
                                                      att + (size_t)L * HEADS * CPH,
                                                      gs + (size_t)L * HID, bs + (size_t)L * HID,
                                                      h, out, (L == 1) ? 1 : 0);
    }
}

// Round 9
// 291.509 us; speedup vs baseline: 1.6440x; 1.0456x over previous
//
#include <hip/hip_runtime.h>
#include <hip/hip_bf16.h>

#define N_NODES 50000
#define E_EDGES 800000
#define ET (E_EDGES + N_NODES)   /* 850000 edges incl self loops */
#define IN_DIM 128
#define HID 96
#define HEADS 2
#define CPH 48
#define NEG_SLOPE 0.2f
#define LN_EPS 1e-5f
#define CHUNK 24                 /* edges per softmax/agg chunk */
#define LROW 50                  /* LDS dwords per staged edge row (48 payload + 2 pad) */
#define PBASE (CHUNK * LROW)     /* start of p area, dwords */
#define WTILE (PBASE + 2 * CHUNK)/* per-wave LDS dwords: 1248 -> 4992 B */
#define WPTOT (IN_DIM * HID)     /* 12288 = KS4 * NT6 * 512 */
#define WCTOT (HID * 2 * HID)    /* 18432 = KS3 * NT12 * 512, per layer */

typedef __hip_bfloat16 bf16;
typedef short bf16x8 __attribute__((ext_vector_type(8)));
typedef float f32x4 __attribute__((ext_vector_type(4)));
typedef _Float16 h16;
typedef h16 h16x2 __attribute__((ext_vector_type(2)));
typedef h16 h16x8 __attribute__((ext_vector_type(8)));

#if __has_builtin(__builtin_amdgcn_fdot2)
#define HAS_FDOT2 1
#else
#define HAS_FDOT2 0
#endif

__device__ __forceinline__ unsigned short f2bf(float f) {
    union { float f; unsigned int i; } u; u.f = f;
    unsigned int r = u.i + 0x7FFFu + ((u.i >> 16) & 1u);
    return (unsigned short)(r >> 16);
}

// ---- DPP reductions (VALU pipe, not LDS pipe — __shfl_* lower to ds_swizzle/bpermute) ----
// row_shr:N = 0x110|N ; row_bcast15 = 0x142 ; row_bcast31 = 0x143
template<int CTRL>
__device__ __forceinline__ float dpp_add(float v) {
    int m = __builtin_amdgcn_update_dpp(0, __builtin_bit_cast(int, v), CTRL, 0xf, 0xf, false);
    return v + __builtin_bit_cast(float, m);
}
template<int CTRL>
__device__ __forceinline__ float dpp_max(float v) {
    int ninf = __builtin_bit_cast(int, -INFINITY);
    int m = __builtin_amdgcn_update_dpp(ninf, __builtin_bit_cast(int, v), CTRL, 0xf, 0xf, false);
    return fmaxf(v, __builtin_bit_cast(float, m));
}
// after: lane31 = reduce(lanes 0..31), lane63 = reduce(lanes 32..63)
__device__ __forceinline__ float half_sum(float v) {
    v = dpp_add<0x111>(v); v = dpp_add<0x112>(v); v = dpp_add<0x114>(v);
    v = dpp_add<0x118>(v); v = dpp_add<0x142>(v);
    return v;
}
__device__ __forceinline__ float half_max(float v) {
    v = dpp_max<0x111>(v); v = dpp_max<0x112>(v); v = dpp_max<0x114>(v);
    v = dpp_max<0x118>(v); v = dpp_max<0x142>(v);
    return v;
}
// full 64-lane sum, result at lane 63
__device__ __forceinline__ float wave_sum(float v) {
    v = half_sum(v); v = dpp_add<0x143>(v);
    return v;
}
__device__ __forceinline__ float rlane(float v, int lane) {
    return __builtin_bit_cast(float, __builtin_amdgcn_readlane(__builtin_bit_cast(int, v), lane));
}

// ---------------- CSR build ----------------
__global__ void k_hist(const int* __restrict__ ei, int* __restrict__ deg) {
    int e = blockIdx.x * blockDim.x + threadIdx.x;
    if (e >= ET) return;
    int dst = (e < E_EDGES) ? ei[E_EDGES + e] : (e - E_EDGES);
    atomicAdd(&deg[dst], 1);
}

// single-block scan, 4 elements/thread (13 iterations over 50k)
__global__ __launch_bounds__(1024) void k_scan(const int* __restrict__ deg,
                                               int* __restrict__ rowstart,
                                               int* __restrict__ cursor) {
    __shared__ int wsum[16];
    __shared__ int s_carry;
    int t = threadIdx.x, lane = t & 63, w = t >> 6;
    if (t == 0) s_carry = 0;
    __syncthreads();
    for (int base = 0; base < N_NODES; base += 4096) {
        int i0 = base + t * 4;
        int4 d = {0, 0, 0, 0};
        if (i0 + 3 < N_NODES) d = *(const int4*)(deg + i0);
        else {
            if (i0 + 0 < N_NODES) d.x = deg[i0 + 0];
            if (i0 + 1 < N_NODES) d.y = deg[i0 + 1];
            if (i0 + 2 < N_NODES) d.z = deg[i0 + 2];
            if (i0 + 3 < N_NODES) d.w = deg[i0 + 3];
        }
        int e1 = d.x, e2 = d.x + d.y, e3 = d.x + d.y + d.z;
        int tot = e3 + d.w;
        int sv = tot;
        for (int o = 1; o < 64; o <<= 1) { int u = __shfl_up(sv, o, 64); if (lane >= o) sv += u; }
        if (lane == 63) wsum[w] = sv;
        __syncthreads();
        if (w == 0) {
            int val = (lane < 16) ? wsum[lane] : 0;
            int s2 = val;
            for (int o = 1; o < 64; o <<= 1) { int u = __shfl_up(s2, o, 64); if (lane >= o) s2 += u; }
            if (lane < 16) wsum[lane] = s2 - val;            // exclusive wave prefix
        }
        __syncthreads();
        int excl = s_carry + wsum[w] + (sv - tot);
        if (i0 + 3 < N_NODES) {
            int4 r = {excl, excl + e1, excl + e2, excl + e3};
            *(int4*)(rowstart + i0) = r;
            *(int4*)(cursor + i0) = r;
        } else {
            if (i0 + 0 < N_NODES) { rowstart[i0 + 0] = excl;      cursor[i0 + 0] = excl; }
            if (i0 + 1 < N_NODES) { rowstart[i0 + 1] = excl + e1; cursor[i0 + 1] = excl + e1; }
            if (i0 + 2 < N_NODES) { rowstart[i0 + 2] = excl + e2; cursor[i0 + 2] = excl + e2; }
            if (i0 + 3 < N_NODES) { rowstart[i0 + 3] = excl + e3; cursor[i0 + 3] = excl + e3; }
        }
        __syncthreads();
        if (t == 1023) s_carry += wsum[15] + sv;
        __syncthreads();
    }
    if (t == 0) rowstart[N_NODES] = ET;
}

__global__ void k_scatter(const int* __restrict__ ei, int* __restrict__ cursor,
                          int* __restrict__ csr_src) {
    int e = blockIdx.x * blockDim.x + threadIdx.x;
    if (e >= ET) return;
    int src, dst;
    if (e < E_EDGES) { src = ei[e]; dst = ei[E_EDGES + e]; }
    else             { src = dst = e - E_EDGES; }
    int pos = atomicAdd(&cursor[dst], 1);
    csr_src[pos] = src;
}

// ---------------- merged weight prep (all 3 GEMM weight sets) + deg zeroing ----------------
__global__ void k_wprep_all(const float* __restrict__ Wp,
                            const float* __restrict__ Wl,
                            const float* __restrict__ Wr,
                            unsigned short* __restrict__ wp_frag,
                            unsigned short* __restrict__ wc_frag,
                            int* __restrict__ deg) {
    int idx = blockIdx.x * blockDim.x + threadIdx.x;
    if (idx < N_NODES) deg[idx] = 0;
    if (idx < WPTOT) {
        int j = idx & 7, lane = (idx >> 3) & 63;
        int nt = (idx >> 9) % 6, ks = (idx >> 9) / 6;
        int k = ks * 32 + ((lane >> 4) << 3) + j;
        int col = nt * 16 + (lane & 15);
        wp_frag[idx] = f2bf(Wp[k * HID + col]);           // col always < 96 (NT=6)
    } else if (idx < WPTOT + 2 * WCTOT) {
        int L = (idx - WPTOT) / WCTOT;
        int id = (idx - WPTOT) % WCTOT;
        int j = id & 7, lane = (id >> 3) & 63;
        int nt = (id >> 9) % 12, ks = (id >> 9) / 12;
        int k = ks * 32 + ((lane >> 4) << 3) + j;
        int col = nt * 16 + (lane & 15);
        const float* W0 = Wl + (size_t)L * HID * HID;
        const float* W1 = Wr + (size_t)L * HID * HID;
        float v = (col < HID) ? W0[k * HID + col] : W1[k * HID + col - HID];
        wc_frag[(size_t)L * WCTOT + id] = f2bf(v);
    }
}

// ---------------- MFMA GEMM: A[f32, MxK] @ Bfrag -> proj(LN+ReLU->h) or xfm(->xl,xr fp16) ----------------
template<int K, int NT, bool PROJ>
__global__ __launch_bounds__(256) void k_gemm(const float* __restrict__ A,
                                              const unsigned short* __restrict__ Bfrag,
                                              const float* __restrict__ bp,
                                              const float* __restrict__ g0,
                                              const float* __restrict__ b0,
                                              float* __restrict__ hout,
                                              h16* __restrict__ xl,
                                              h16* __restrict__ xr) {
    constexpr int KS = K / 32;
    int t = threadIdx.x, l = t & 63, w = t >> 6;
    int row0 = blockIdx.x * 64 + w * 16;
    int arow = row0 + (l & 15);
    if (arow > N_NODES - 1) arow = N_NODES - 1;
    int kb = (l >> 4) * 8;
    const float* ap = A + (long)arow * K + kb;
    bf16x8 a[KS];
    #pragma unroll
    for (int ks = 0; ks < KS; ks++) {
        float4 f0 = *(const float4*)(ap + ks * 32);
        float4 f1 = *(const float4*)(ap + ks * 32 + 4);
        bf16x8 av;
        av[0] = (short)f2bf(f0.x); av[1] = (short)f2bf(f0.y);
        av[2] = (short)f2bf(f0.z); av[3] = (short)f2bf(f0.w);
        av[4] = (short)f2bf(f1.x); av[5] = (short)f2bf(f1.y);
        av[6] = (short)f2bf(f1.z); av[7] = (short)f2bf(f1.w);
        a[ks] = av;
    }
    f32x4 acc[NT];
    #pragma unroll
    for (int nt = 0; nt < NT; nt++) acc[nt] = (f32x4){0.f, 0.f, 0.f, 0.f};
    #pragma unroll
    for (int nt = 0; nt < NT; nt++) {
        #pragma unroll
        for (int ks = 0; ks < KS; ks++) {
            bf16x8 b = *(const bf16x8*)(Bfrag + (((long)(ks * NT + nt) * 64 + l) << 3));
            acc[nt] = __builtin_amdgcn_mfma_f32_16x16x32_bf16(a[ks], b, acc[nt], 0, 0, 0);
        }
    }
    int rg = l >> 4, cl = l & 15;
    if constexpr (PROJ) {
        float bpv[NT], g0v[NT], b0v[NT];
        #pragma unroll
        for (int nt = 0; nt < NT; nt++) {
            int col = nt * 16 + cl;
            bpv[nt] = bp[col]; g0v[nt] = g0[col]; b0v[nt] = b0[col];
        }
        #pragma unroll
        for (int r = 0; r < 4; r++) {
            float s = 0.f, sq = 0.f;
            #pragma unroll
            for (int nt = 0; nt < NT; nt++) {
                float v = acc[nt][r] + bpv[nt];
                acc[nt][r] = v; s += v; sq += v * v;
            }
            #pragma unroll
            for (int o = 1; o <= 8; o <<= 1) { s += __shfl_xor(s, o, 64); sq += __shfl_xor(sq, o, 64); }
            float mu = s / (float)HID;
            float var = sq / (float)HID - mu * mu;
            float rstd = rsqrtf(var + LN_EPS);
            int row = row0 + rg * 4 + r;
            if (row < N_NODES) {
                #pragma unroll
                for (int nt = 0; nt < NT; nt++) {
                    float y = (acc[nt][r] - mu) * rstd * g0v[nt] + b0v[nt];
                    hout[(long)row * HID + nt * 16 + cl] = fmaxf(y, 0.f);
                }
            }
        }
    } else {
        #pragma unroll
        for (int r = 0; r < 4; r++) {
            int row = row0 + rg * 4 + r;
            if (row < N_NODES) {
                #pragma unroll
                for (int nt = 0; nt < NT; nt++) {
                    int col = nt * 16 + cl;
                    h16 v = (h16)acc[nt][r];
                    if (col < HID) xl[(long)row * HID + col] = v;
                    else           xr[(long)row * HID + col - HID] = v;
                }
            }
        }
    }
}

// ---------------- fused: edge scores + online softmax + aggregate + LN + ELU + residual ----------------
// One wave per node; 4 waves/block; no __syncthreads. All reductions via DPP (VALU pipe);
// (M0,M1,D0,D1) tracked redundantly-uniform in every lane via readlane — zero shuffles.
// LDS pipe now only carries the stage/read dataflow (6 wr + 7 p + 24 agg per chunk).
__global__ __launch_bounds__(256) void k_node_fused(const int* __restrict__ rowstart,
                                                    const int* __restrict__ csr_src,
                                                    const h16* __restrict__ xl,
                                                    const h16* __restrict__ xr,
                                                    const float* __restrict__ att,
                                                    const float* __restrict__ gs,
                                                    const float* __restrict__ bs,
                                                    float* __restrict__ h,
                                                    float* __restrict__ out,
                                                    int write_out) {
    __shared__ float lds[4 * WTILE];
    int t = threadIdx.x, lane = t & 63, w = t >> 6;
    float* slds = lds + w * WTILE;                 // x-stage: edge i at dwords [i*LROW .. +47]
    float* pbuf = slds + PBASE;                    // p: head hh at [hh*CHUNK + j]
    int n = blockIdx.x * 4 + w;                    // grid = N/4 exact
    int j = lane & 31, hh = lane >> 5;
    bool jok = (j < CHUNK);
    int rs = rowstart[n], re = rowstart[n + 1];

    const h16x8* xrr = (const h16x8*)(xr + (long)n * HID + hh * CPH);
    h16x8 xrv[6];
    #pragma unroll
    for (int v = 0; v < 6; v++) xrv[v] = xrr[v];
    const float* ar = att + hh * CPH;
    h16x8 attv[6];
    #pragma unroll
    for (int v = 0; v < 6; v++) {
        float4 t0 = *(const float4*)(ar + v * 8);
        float4 t1 = *(const float4*)(ar + v * 8 + 4);
        attv[v] = (h16x8){(h16)t0.x, (h16)t0.y, (h16)t0.z, (h16)t0.w,
                          (h16)t1.x, (h16)t1.y, (h16)t1.z, (h16)t1.w};
    }

    float M0 = -INFINITY, M1 = -INFINITY, D0 = 0.f, D1 = 0.f;   // uniform in all lanes
    int l = lane;
    int lc = (l < 48) ? l : 47;                    // channel pair owned (lanes>=48 shadow 47)
    bool hi = (lc >= 24);                          // which head's p/D this lane consumes
    float2 acc = {0.f, 0.f};

    for (int base = rs; base < re; base += CHUNK) {
        int L = min(CHUNK, re - base);
        float s = -INFINITY;
        if (jok) {
            int srcj = csr_src[base + min(j, L - 1)];
            const h16x8* xlr = (const h16x8*)(xl + (long)srcj * HID + hh * CPH);
            float s0 = 0.f, s1 = 0.f;
#if !HAS_FDOT2
            h16x8 sacc = (h16x8)(h16)0.f;
#endif
            #pragma unroll
            for (int v = 0; v < 6; v++) {
                h16x8 xa = xlr[v];
                *(h16x8*)(slds + j * LROW + hh * 24 + v * 4) = xa;   // stage (offset-imm)
                h16x8 sum = xa + xrv[v];
                h16x8 lk = __builtin_elementwise_max(sum, sum * (h16)NEG_SLOPE);
#if HAS_FDOT2
                s0 = __builtin_amdgcn_fdot2(__builtin_shufflevector(lk, lk, 0, 1),
                                            __builtin_shufflevector(attv[v], attv[v], 0, 1), s0, false);
                s1 = __builtin_amdgcn_fdot2(__builtin_shufflevector(lk, lk, 2, 3),
                                            __builtin_shufflevector(attv[v], attv[v], 2, 3), s1, false);
                s0 = __builtin_amdgcn_fdot2(__builtin_shufflevector(lk, lk, 4, 5),
                                            __builtin_shufflevector(attv[v], attv[v], 4, 5), s0, false);
                s1 = __builtin_amdgcn_fdot2(__builtin_shufflevector(lk, lk, 6, 7),
                                            __builtin_shufflevector(attv[v], attv[v], 6, 7), s1, false);
#else
                sacc += lk * attv[v];
#endif
            }
#if !HAS_FDOT2
            {
                h16x2 p0 = __builtin_shufflevector(sacc, sacc, 0, 1);
                h16x2 p1 = __builtin_shufflevector(sacc, sacc, 2, 3);
                h16x2 p2 = __builtin_shufflevector(sacc, sacc, 4, 5);
                h16x2 p3 = __builtin_shufflevector(sacc, sacc, 6, 7);
                h16x2 q = (p0 + p1) + (p2 + p3);
                s0 = (float)q.x + (float)q.y; s1 = 0.f;
            }
#endif
            if (j < L) s = s0 + s1;
        }
        // online softmax update — DPP half-reduce + readlane, no LDS-pipe ops
        float mh = half_max(s);
        float m0 = rlane(mh, 31), m1 = rlane(mh, 63);
        float nM0 = fmaxf(M0, m0), nM1 = fmaxf(M1, m1);
        float sc0 = __expf(M0 - nM0), sc1 = __expf(M1 - nM1);   // exp(-inf)=0 first chunk
        float myM = (lane < 32) ? nM0 : nM1;
        float p = (jok && j < L) ? __expf(s - myM) : 0.f;
        float sh = half_sum(p);
        float sum0 = rlane(sh, 31), sum1 = rlane(sh, 63);
        D0 = D0 * sc0 + sum0; D1 = D1 * sc1 + sum1;
        M0 = nM0; M1 = nM1;
        if (jok) pbuf[hh * CHUNK + j] = p;          // padding slots get p=0

        float mysc = hi ? sc1 : sc0;
        acc.x *= mysc; acc.y *= mysc;

        const float* prow = pbuf + (hi ? CHUNK : 0);
        #pragma unroll
        for (int i4 = 0; i4 < CHUNK / 4; i4++) {
            if (i4 * 4 >= L) break;
            float4 pv = *(const float4*)(prow + i4 * 4);
            #pragma unroll
            for (int k = 0; k < 4; k++) {
                h16x2 hv = ((const h16x2*)(slds + (i4 * 4 + k) * LROW))[lc];
                float pk = ((const float*)&pv)[k];
                acc.x += pk * (float)hv.x;
                acc.y += pk * (float)hv.y;
            }
        }
    }
    float myD = hi ? D1 : D0;
    float oa = acc.x / myD, ob = acc.y / myD;
    bool act = (l < 48);
    if (!act) { oa = 0.f; ob = 0.f; }
    // LayerNorm over 96 channels — DPP full-wave reduce
    float s1r = wave_sum(oa + ob);
    float s2r = wave_sum(oa * oa + ob * ob);
    float mu = rlane(s1r, 63) / (float)HID;
    float var = rlane(s2r, 63) / (float)HID - mu * mu;
    float rstd = rsqrtf(var + LN_EPS);
    if (act) {
        long baseo = (long)n * HID + 2 * l;
        float2 g = *(const float2*)(gs + 2 * l);
        float2 b = *(const float2*)(bs + 2 * l);
        float y0 = (oa - mu) * rstd * g.x + b.x;
        float y1 = (ob - mu) * rstd * g.y + b.y;
        float hn0 = (y0 > 0.f) ? y0 : expm1f(y0);
        float hn1 = (y1 > 0.f) ? y1 : expm1f(y1);
        float2 hold = *(float2*)(h + baseo);
        float2 hv = {hold.x + hn0, hold.y + hn1};
        *(float2*)(h + baseo) = hv;
        if (write_out) *(float2*)(out + baseo) = hv;
    }
}

extern "C" void kernel_launch(void* const* d_in, const int* in_sizes, int n_in,
                              void* d_out, int out_size, void* d_ws, size_t ws_size,
                              hipStream_t stream) {
    const float* x   = (const float*)d_in[0];
    const int*   ei  = (const int*)d_in[1];
    const float* Wp  = (const float*)d_in[2];
    const float* bp  = (const float*)d_in[3];
    const float* g0  = (const float*)d_in[4];
    const float* b0  = (const float*)d_in[5];
    const float* Wl  = (const float*)d_in[6];
    const float* Wr  = (const float*)d_in[7];
    const float* att = (const float*)d_in[8];
    const float* gs  = (const float*)d_in[9];
    const float* bs  = (const float*)d_in[10];
    float* out = (float*)d_out;

    char* wsp = (char*)d_ws;
    size_t off = 0;
    auto alloc = [&](size_t bytes) { void* p = wsp + off; off += (bytes + 255) / 256 * 256; return p; };
    float* h        = (float*)alloc((size_t)N_NODES * HID * 4);
    h16*   xl       = (h16*)  alloc((size_t)N_NODES * HID * 2);
    h16*   xr       = (h16*)  alloc((size_t)N_NODES * HID * 2);
    int*   deg      = (int*)  alloc((size_t)N_NODES * 4);
    int*   rowst    = (int*)  alloc((size_t)(N_NODES + 1) * 4);
    int*   cursor   = (int*)  alloc((size_t)N_NODES * 4);
    int*   csr_src  = (int*)  alloc((size_t)ET * 4);
    unsigned short* wp_frag = (unsigned short*)alloc((size_t)WPTOT * 2);
    unsigned short* wc_frag = (unsigned short*)alloc((size_t)2 * WCTOT * 2);

    k_wprep_all<<<(N_NODES + 255) / 256, 256, 0, stream>>>(Wp, Wl, Wr, wp_frag, wc_frag, deg);
    k_hist<<<(ET + 255) / 256, 256, 0, stream>>>(ei, deg);
    k_scan<<<1, 1024, 0, stream>>>(deg, rowst, cursor);
    k_scatter<<<(ET + 255) / 256, 256, 0, stream>>>(ei, cursor, csr_src);

    const int GBLK = (N_NODES + 63) / 64;
    k_gemm<IN_DIM, 6, true><<<GBLK, 256, 0, stream>>>(x, wp_frag, bp, g0, b0, h, nullptr, nullptr);
    for (int L = 0; L < 2; L++) {
        k_gemm<HID, 12, false><<<GBLK, 256, 0, stream>>>(h, wc_frag + (size_t)L * WCTOT,
                                                         nullptr, nullptr, nullptr, nullptr, xl, xr);
        k_node_fused<<<N_NODES / 4, 256, 0, stream>>>(rowst, csr_src, xl, xr,
                                                      att + (size_t)L * HEADS * CPH,
                                                      gs + (size_t)L * HID, bs + (size_t)L * HID,
                                                      h, out, (L == 1) ? 1 : 0);
    }
}